// Round 8
// baseline (1123.761 us; speedup 1.0000x reference)
//
#include <hip/hip_runtime.h>
#include <hip/hip_bf16.h>
#include <stdint.h>

#define DIM_H 2048
#define DIM_I 8192
#define TOKENS 8192
#define RB256 34            // max 256-row compacted blocks (32 + 2 pad)
#define CROWS (RB256*256)   // 8704

typedef __attribute__((ext_vector_type(8))) short bf16x8;
typedef __attribute__((ext_vector_type(16))) float f32x16;

#define MF32(a,b,c) __builtin_amdgcn_mfma_f32_32x32x16_bf16((a),(b),(c),0,0,0)

__device__ __forceinline__ unsigned short f2bf(float f) {
    union { float f; unsigned u; } v; v.f = f;
    return (unsigned short)((v.u + 0x7FFF + ((v.u >> 16) & 1)) >> 16);
}

// ---------------- fp32 -> bf16 conversion ----------------
__global__ __launch_bounds__(256) void cvt_kernel(const float* __restrict__ in,
                                                  unsigned short* __restrict__ out,
                                                  int n4) {
    int stride = gridDim.x * blockDim.x;
    for (int j = blockIdx.x * blockDim.x + threadIdx.x; j < n4; j += stride) {
        float4 v = reinterpret_cast<const float4*>(in)[j];
        ushort4 o;
        o.x = f2bf(v.x); o.y = f2bf(v.y); o.z = f2bf(v.z); o.w = f2bf(v.w);
        reinterpret_cast<ushort4*>(out)[j] = o;
    }
}

// interleave gate/up weights at 32-row granularity:
// W13[64g + j] = w1[32g + j]; W13[64g + 32 + j] = w3[32g + j]
__global__ __launch_bounds__(256) void cvt13_kernel(const float* __restrict__ w1,
                                                    const float* __restrict__ w3,
                                                    unsigned short* __restrict__ W13,
                                                    int n4) {
    int stride = gridDim.x * blockDim.x;
    for (int j = blockIdx.x * blockDim.x + threadIdx.x; j < n4; j += stride) {
        int flat = j << 2;
        int R = flat >> 11;          // row (DIM_H = 2048 cols)
        int col = flat & 2047;
        int orow = ((R >> 5) << 6) | (R & 31);
        float4 v1 = reinterpret_cast<const float4*>(w1)[j];
        float4 v3 = reinterpret_cast<const float4*>(w3)[j];
        ushort4 o1, o3;
        o1.x=f2bf(v1.x); o1.y=f2bf(v1.y); o1.z=f2bf(v1.z); o1.w=f2bf(v1.w);
        o3.x=f2bf(v3.x); o3.y=f2bf(v3.y); o3.z=f2bf(v3.z); o3.w=f2bf(v3.w);
        *reinterpret_cast<ushort4*>(&W13[(size_t)orow * DIM_H + col]) = o1;
        *reinterpret_cast<ushort4*>(&W13[(size_t)(orow + 32) * DIM_H + col]) = o3;
    }
}

// ---------------- mask compaction (256-row padding) ----------------
__global__ __launch_bounds__(256) void compact_kernel(const int* __restrict__ mask,
                                                      int* __restrict__ idx,
                                                      int* __restrict__ hdr) {
    __shared__ int cnt[256];
    const int t = threadIdx.x;
    const int base = t * 32;
    unsigned bits = 0;
#pragma unroll
    for (int j = 0; j < 32; ++j)
        if (mask[base + j] != 0) bits |= (1u << j);
    const int c = __popc(bits);
    cnt[t] = c;
    __syncthreads();
    for (int off = 1; off < 256; off <<= 1) {
        int v = cnt[t];
        int add = (t >= off) ? cnt[t - off] : 0;
        __syncthreads();
        cnt[t] = v + add;
        __syncthreads();
    }
    const int Mw  = cnt[255];
    const int MwP = (Mw + 255) & ~255;
    const int Mu  = TOKENS - Mw;
    const int MuP = (Mu + 255) & ~255;

    for (int j = t; j < CROWS; j += 256) idx[j] = -1;
    __syncthreads();

    int pw = cnt[t] - c;
    int pz = base - pw;
#pragma unroll
    for (int j = 0; j < 32; ++j) {
        int tok = base + j;
        if ((bits >> j) & 1) idx[pw++] = tok;
        else                 idx[MwP + pz++] = tok;
    }
    if (t == 0) {
        hdr[0] = MwP >> 8;           // w-blocks (256-row units)
        hdr[1] = (MwP + MuP) >> 8;   // total blocks
        hdr[2] = Mw;
        hdr[3] = Mu;
    }
}

// ================= shared 32x32x16 GEMM machinery =================
// LDS slice = R rows x 32 k bf16 (64B rows); swizzle (16B units): phys c16' = c16 ^ ((row>>1)&3)
// applied on pre-swizzled global src (linear gll dest) + on ds_read addr.
// A/B frag (32x32x16): row = lane&31, k = 8*(lane>>5)+j  -> 1 b128/frag
// off0/off1 = per-lane elem offset for k-half slot {0,1}/{2,3} of a slice.

#define STAGE2(UB_, S0_, S1_, KOFS_) do { \
    __builtin_amdgcn_global_load_lds((const __attribute__((address_space(1))) void*)((S0_) + (KOFS_)), \
        (__attribute__((address_space(3))) void*)&smem[(UB_) + wave*512], 16, 0, 0); \
    __builtin_amdgcn_global_load_lds((const __attribute__((address_space(1))) void*)((S1_) + (KOFS_)), \
        (__attribute__((address_space(3))) void*)&smem[(UB_) + 4096 + wave*512], 16, 0, 0); \
} while(0)

#define STAGE1(UB_, S0_, KOFS_) \
    __builtin_amdgcn_global_load_lds((const __attribute__((address_space(1))) void*)((S0_) + (KOFS_)), \
        (__attribute__((address_space(3))) void*)&smem[(UB_) + wave*512], 16, 0, 0)

#define RD(V, EO) V = *reinterpret_cast<const bf16x8*>(&smem[(EO)])

// ---------------- GEMM1: 256x256 / BK=64 / 8 waves (2Mx4N) / frag-pipelined ----------------
// LDS 128KB: 2 buf x { A0(8192), A1, B0, B1 } elems. Wave out: 128x64 = 4m x 2n of 32x32.
#define G1_RDA(V0,V1,V2,V3, SB, OFF) do { \
    RD(V0, (SB) + wrM*4096 +    0 + (OFF)); \
    RD(V1, (SB) + wrM*4096 + 1024 + (OFF)); \
    RD(V2, (SB) + wrM*4096 + 2048 + (OFF)); \
    RD(V3, (SB) + wrM*4096 + 3072 + (OFF)); \
} while(0)
#define G1_RDB(V0,V1, SB, OFF) do { \
    RD(V0, (SB) + wcN*2048 +    0 + (OFF)); \
    RD(V1, (SB) + wcN*2048 + 1024 + (OFF)); \
} while(0)
#define G1_MFMA(A0,A1,A2,A3,B0,B1) do { \
    __builtin_amdgcn_s_setprio(1); \
    acc00=MF32(A0,B0,acc00); acc01=MF32(A0,B1,acc01); \
    acc10=MF32(A1,B0,acc10); acc11=MF32(A1,B1,acc11); \
    acc20=MF32(A2,B0,acc20); acc21=MF32(A2,B1,acc21); \
    acc30=MF32(A3,B0,acc30); acc31=MF32(A3,B1,acc31); \
    __builtin_amdgcn_s_setprio(0); \
} while(0)

__global__ __launch_bounds__(512, 2) void gemm1_kernel(
    const unsigned short* __restrict__ xb,
    const unsigned short* __restrict__ W13,
    const unsigned short* __restrict__ U13,
    const int* __restrict__ idx, const int* __restrict__ hdr,
    unsigned short* __restrict__ P)
{
    __shared__ __align__(16) unsigned short smem[65536];  // 128 KB
    const int wB  = hdr[0];
    const int rbT = hdr[1];
    const int nwg = gridDim.x;
    const int q8  = nwg >> 3;
    const int swzb = ((int)blockIdx.x & 7) * q8 + ((int)blockIdx.x >> 3);
    const int rb = swzb % RB256;               // M-block fast within XCD chunk
    const int bx = swzb / RB256;
    if (rb >= rbT) return;
    const unsigned short* Bm = (rb < wB) ? W13 : U13;
    const int bm0 = rb << 8;
    const int bn0 = bx << 8;

    const int tid  = threadIdx.x;
    const int lane = tid & 63;
    const int wave = tid >> 6;
    const int wrM = wave >> 2;                 // 0..1
    const int wcN = wave & 3;                  // 0..3
    const int kh   = lane >> 5;                // k-half within 16-k slice
    const int swz  = (lane >> 1) & 3;          // read-side XOR key
    const int off0 = (lane & 31) * 32 + ((kh ^ swz) << 3);
    const int off1 = (lane & 31) * 32 + (((2 + kh) ^ swz) << 3);

    // staging source addresses (pre-swizzled global col)
    const int r0 = tid >> 2, r1 = 128 + r0;
    const int c0 = ((tid & 3) ^ ((r0 >> 1) & 3)) << 3;
    const int c1 = ((tid & 3) ^ ((r1 >> 1) & 3)) << 3;
    int t0 = idx[bm0 + r0]; if (t0 < 0) t0 = 0;
    int t1 = idx[bm0 + r1]; if (t1 < 0) t1 = 0;
    const unsigned short* sa0 = xb + (size_t)t0 * DIM_H + c0;
    const unsigned short* sa1 = xb + (size_t)t1 * DIM_H + c1;
    const unsigned short* sb0 = Bm + (size_t)(bn0 + r0) * DIM_H + c0;
    const unsigned short* sb1 = Bm + (size_t)(bn0 + r1) * DIM_H + c1;

    f32x16 acc00 = {}, acc01 = {}, acc10 = {}, acc11 = {};
    f32x16 acc20 = {}, acc21 = {}, acc30 = {}, acc31 = {};
    bf16x8 xa0, xa1, xa2, xa3, xb0, xb1;
    bf16x8 ya0, ya1, ya2, ya3, yb0, yb1;

    // prologue: t0 {k0,k1}, t1 {k0}
    STAGE2(0,     sa0, sa1, 0);
    STAGE2(16384, sb0, sb1, 0);
    STAGE2(8192,  sa0, sa1, 32);
    STAGE2(24576, sb0, sb1, 32);
    STAGE2(32768, sa0, sa1, 64);
    STAGE2(49152, sb0, sb1, 64);
    asm volatile("s_waitcnt vmcnt(8)" ::: "memory");   // t0.k0 ready
    __builtin_amdgcn_s_barrier();
    // X <- (t0, s0)
    G1_RDA(xa0,xa1,xa2,xa3, 0,     off0);
    G1_RDB(xb0,xb1,        16384,  off0);
    int ko2 = 96, ko6 = 128;
    for (int t = 0; t < 32; ++t) {
        const int cur = (t & 1) << 15;
        const int nxt = cur ^ 32768;
        // s1 reads overlap s0 MFMA
        G1_RDA(ya0,ya1,ya2,ya3, cur,         off1);
        G1_RDB(yb0,yb1,         cur + 16384, off1);
        STAGE2(nxt + 8192,  sa0, sa1, ko2);      // (t+1).k1
        STAGE2(nxt + 24576, sb0, sb1, ko2);
        G1_MFMA(xa0,xa1,xa2,xa3, xb0,xb1);       // s0
        asm volatile("s_waitcnt vmcnt(8)" ::: "memory");  // t.k1 landed
        __builtin_amdgcn_s_barrier();            // k0 reads issued by all waves
        // s2 reads overlap s1 MFMA
        G1_RDA(xa0,xa1,xa2,xa3, cur + 8192,  off0);
        G1_RDB(xb0,xb1,         cur + 24576, off0);
        STAGE2(cur,         sa0, sa1, ko6);      // (t+2).k0 over freed slice
        STAGE2(cur + 16384, sb0, sb1, ko6);
        G1_MFMA(ya0,ya1,ya2,ya3, yb0,yb1);       // s1
        // s3 reads overlap s2 MFMA
        G1_RDA(ya0,ya1,ya2,ya3, cur + 8192,  off1);
        G1_RDB(yb0,yb1,         cur + 24576, off1);
        G1_MFMA(xa0,xa1,xa2,xa3, xb0,xb1);       // s2
        asm volatile("s_waitcnt vmcnt(8)" ::: "memory");  // (t+1).k0 landed
        __builtin_amdgcn_s_barrier();            // k1 reads issued by all waves
        // (t+1,s0) reads overlap s3 MFMA
        G1_RDA(xa0,xa1,xa2,xa3, nxt,         off0);
        G1_RDB(xb0,xb1,         nxt + 16384, off0);
        G1_MFMA(ya0,ya1,ya2,ya3, yb0,yb1);       // s3
        ko2 += 64; ko6 += 64;
    }

    // epilogue: n-frag 0 = h1, n-frag 1 = h3 for the same 32 P-cols
    // C/D: col = lane&31, row = (reg&3) + 8*(reg>>2) + 4*kh
    const int kh4 = kh << 2;
    unsigned short* Pw = P + (size_t)(bm0 + wrM * 128) * DIM_I
                           + (size_t)bx * 128 + wcN * 32 + (lane & 31);
#define G1EPI(H1, H3, M) do { \
    _Pragma("unroll") \
    for (int reg = 0; reg < 16; ++reg) { \
        float a = H1[reg]; \
        float p = a * (1.0f / (1.0f + __expf(-a))) * H3[reg]; \
        int rr = (reg & 3) + ((reg >> 2) << 3) + kh4; \
        Pw[(size_t)((M) * 32 + rr) * DIM_I] = f2bf(p); \
    } } while(0)
    G1EPI(acc00, acc01, 0);
    G1EPI(acc10, acc11, 1);
    G1EPI(acc20, acc21, 2);
    G1EPI(acc30, acc31, 3);
#undef G1EPI
}

// ---------------- GEMM2: 128x256 / BK=64 / 8 waves (2Mx4N) / triple-buffer frag-pipelined ----
// LDS 144KB: 3 buf x { A0(4096), A1(4096), B0(8192), B1(8192) } = 24576 elems each.
// Wave out: 64x64 = 2m x 2n of 32x32.
#define G2_RDA(V0,V1, SB, OFF) do { \
    RD(V0, (SB) + wrM*2048 +    0 + (OFF)); \
    RD(V1, (SB) + wrM*2048 + 1024 + (OFF)); \
} while(0)
#define G2_RDB(V0,V1, SB, OFF) do { \
    RD(V0, (SB) + wcN*2048 +    0 + (OFF)); \
    RD(V1, (SB) + wcN*2048 + 1024 + (OFF)); \
} while(0)
#define G2_MFMA(A0,A1,B0,B1) do { \
    __builtin_amdgcn_s_setprio(1); \
    acc00=MF32(A0,B0,acc00); acc01=MF32(A0,B1,acc01); \
    acc10=MF32(A1,B0,acc10); acc11=MF32(A1,B1,acc11); \
    __builtin_amdgcn_s_setprio(0); \
} while(0)

__global__ __launch_bounds__(512, 2) void gemm2_kernel(
    const unsigned short* __restrict__ P,
    const unsigned short* __restrict__ w2b, const unsigned short* __restrict__ u2b,
    const int* __restrict__ idx, const int* __restrict__ hdr,
    float* __restrict__ out)
{
    __shared__ __align__(16) unsigned short smem[73728];  // 144 KB
    const int wB2  = hdr[0] * 2;               // 128-row units
    const int rbT2 = hdr[1] * 2;
    const int nwg = gridDim.x;                 // 544
    const int q8  = nwg >> 3;
    const int swzb = ((int)blockIdx.x & 7) * q8 + ((int)blockIdx.x >> 3);
    const int rb = swzb % 68;                  // M fast: each XCD pins one bx B-panel
    const int bx = swzb / 68;
    if (rb >= rbT2) return;
    const unsigned short* Bm = (rb < wB2) ? w2b : u2b;
    const int bm0 = rb << 7;
    const int bn0 = bx << 8;

    const int tid  = threadIdx.x;
    const int lane = tid & 63;
    const int wave = tid >> 6;
    const int wrM = wave >> 2;
    const int wcN = wave & 3;
    const int kh   = lane >> 5;
    const int swz  = (lane >> 1) & 3;
    const int off0 = (lane & 31) * 32 + ((kh ^ swz) << 3);
    const int off1 = (lane & 31) * 32 + (((2 + kh) ^ swz) << 3);

    const int r0 = tid >> 2, r1 = 128 + r0;
    const int c0 = ((tid & 3) ^ ((r0 >> 1) & 3)) << 3;
    const int c1 = ((tid & 3) ^ ((r1 >> 1) & 3)) << 3;
    const unsigned short* sa0 = P  + (size_t)(bm0 + r0) * DIM_I + c0;   // A rows 0..127
    const unsigned short* sb0 = Bm + (size_t)(bn0 + r0) * DIM_I + c0;
    const unsigned short* sb1 = Bm + (size_t)(bn0 + r1) * DIM_I + c1;

    f32x16 acc00 = {}, acc01 = {}, acc10 = {}, acc11 = {};
    bf16x8 xa0, xa1, xb0, xb1, ya0, ya1, yb0, yb1;

    // prologue: t0 -> buf0, t1 -> buf1 (6 glls each)
    STAGE1(0,     sa0, 0);
    STAGE1(4096,  sa0, 32);
    STAGE2(8192,  sb0, sb1, 0);
    STAGE2(16384, sb0, sb1, 32);
    STAGE1(24576,         sa0, 64);
    STAGE1(24576 + 4096,  sa0, 96);
    STAGE2(24576 + 8192,  sb0, sb1, 64);
    STAGE2(24576 + 16384, sb0, sb1, 96);
    asm volatile("s_waitcnt vmcnt(6)" ::: "memory");
    __builtin_amdgcn_s_barrier();
    G2_RDA(xa0,xa1, 0,    off0);
    G2_RDB(xb0,xb1, 8192, off0);
    int ko = 128, cb = 0;
    for (int t = 0; t < 128; ++t) {
        const int base = cb * 24576;
        int nb = base + 49152; if (nb >= 73728) nb -= 73728;   // (cb+2)%3
        // s1 reads overlap s0 MFMA
        G2_RDA(ya0,ya1, base,        off1);
        G2_RDB(yb0,yb1, base + 8192, off1);
        STAGE1(nb,         sa0, ko);                 // stage t+2
        STAGE1(nb + 4096,  sa0, ko + 32);
        STAGE2(nb + 8192,  sb0, sb1, ko);
        STAGE2(nb + 16384, sb0, sb1, ko + 32);
        G2_MFMA(xa0,xa1, xb0,xb1);                   // s0
        // s2 reads overlap s1 MFMA
        G2_RDA(xa0,xa1, base + 4096,  off0);
        G2_RDB(xb0,xb1, base + 16384, off0);
        G2_MFMA(ya0,ya1, yb0,yb1);                   // s1
        // s3 reads overlap s2 MFMA
        G2_RDA(ya0,ya1, base + 4096,  off1);
        G2_RDB(yb0,yb1, base + 16384, off1);
        G2_MFMA(xa0,xa1, xb0,xb1);                   // s2
        asm volatile("s_waitcnt vmcnt(6)" ::: "memory");  // t+1 fully landed
        __builtin_amdgcn_s_barrier();
        // (t+1,s0) reads overlap s3 MFMA
        int b1 = base + 24576; if (b1 >= 73728) b1 -= 73728;
        G2_RDA(xa0,xa1, b1,        off0);
        G2_RDB(xb0,xb1, b1 + 8192, off0);
        G2_MFMA(ya0,ya1, yb0,yb1);                   // s3
        ko += 64;
        cb = (cb == 2) ? 0 : cb + 1;
    }

    const int kh4 = kh << 2;
    const int colb = bn0 + wcN * 64 + (lane & 31);
#define G2EPI(ACC, M, N) do { \
    _Pragma("unroll") \
    for (int reg = 0; reg < 16; ++reg) { \
        int rr = (reg & 3) + ((reg >> 2) << 3) + kh4; \
        int rowc = bm0 + wrM * 64 + (M) * 32 + rr; \
        int g = idx[rowc]; \
        if (g >= 0) out[(size_t)g * DIM_H + colb + (N) * 32] = ACC[reg]; \
    } } while(0)
    G2EPI(acc00, 0, 0);
    G2EPI(acc01, 0, 1);
    G2EPI(acc10, 1, 0);
    G2EPI(acc11, 1, 1);
#undef G2EPI
}

extern "C" void kernel_launch(void* const* d_in, const int* in_sizes, int n_in,
                              void* d_out, int out_size, void* d_ws, size_t ws_size,
                              hipStream_t stream) {
    const float* x    = (const float*)d_in[0];
    const int*   mask = (const int*)d_in[1];
    const float* w1 = (const float*)d_in[2];
    const float* w2 = (const float*)d_in[3];
    const float* w3 = (const float*)d_in[4];
    const float* u1 = (const float*)d_in[5];
    const float* u2 = (const float*)d_in[6];
    const float* u3 = (const float*)d_in[7];
    float* out = (float*)d_out;

    const size_t XN   = (size_t)TOKENS * DIM_H;      // 16.78M
    const size_t WN   = (size_t)DIM_I * DIM_H;       // 16.78M
    const size_t PN   = (size_t)CROWS * DIM_I;       // 71.3M
    const size_t W13N = 2 * WN;                      // 33.55M

    unsigned short* ws  = (unsigned short*)d_ws;
    unsigned short* xb  = ws;                        // XN
    unsigned short* Pb  = xb + XN;                   // PN
    unsigned short* W13 = Pb + PN;                   // W13N
    unsigned short* U13 = W13 + W13N;                // W13N
    int* idx = (int*)(U13 + W13N);                   // CROWS ints
    int* hdr = idx + CROWS;                          // 8 ints
    unsigned short* w2b = W13;                       // reuse after gemm1
    unsigned short* u2b = U13;

    const int cvtBlocks = 2048;
    const int n4 = (int)(WN / 4);

    cvt_kernel  <<<cvtBlocks, 256, 0, stream>>>(x, xb, (int)(XN / 4));
    cvt13_kernel<<<cvtBlocks, 256, 0, stream>>>(w1, w3, W13, n4);
    cvt13_kernel<<<cvtBlocks, 256, 0, stream>>>(u1, u3, U13, n4);
    compact_kernel<<<1, 256, 0, stream>>>(mask, idx, hdr);

    gemm1_kernel<<<64 * RB256, 512, 0, stream>>>(xb, W13, U13, idx, hdr, Pb);

    cvt_kernel<<<cvtBlocks, 256, 0, stream>>>(w2, w2b, n4);
    cvt_kernel<<<cvtBlocks, 256, 0, stream>>>(u2, u2b, n4);

    gemm2_kernel<<<8 * 68, 512, 0, stream>>>(Pb, w2b, u2b, idx, hdr, out);
}

// Round 9
// 1098.750 us; speedup vs baseline: 1.0228x; 1.0228x over previous
//
#include <hip/hip_runtime.h>
#include <hip/hip_bf16.h>
#include <stdint.h>

#define DIM_H 2048
#define DIM_I 8192
#define TOKENS 8192
#define RB256 34            // max 256-row compacted blocks (32 + 2 pad)
#define CROWS (RB256*256)   // 8704

typedef __attribute__((ext_vector_type(8))) short bf16x8;
typedef __attribute__((ext_vector_type(4))) float f32x4;

#define MF(a,b,c) __builtin_amdgcn_mfma_f32_16x16x32_bf16((a),(b),(c),0,0,0)

__device__ __forceinline__ unsigned short f2bf(float f) {
    union { float f; unsigned u; } v; v.f = f;
    return (unsigned short)((v.u + 0x7FFF + ((v.u >> 16) & 1)) >> 16);
}

// ---------------- fp32 -> bf16 conversion ----------------
__global__ __launch_bounds__(256) void cvt_kernel(const float* __restrict__ in,
                                                  unsigned short* __restrict__ out,
                                                  int n4) {
    int stride = gridDim.x * blockDim.x;
    for (int j = blockIdx.x * blockDim.x + threadIdx.x; j < n4; j += stride) {
        float4 v = reinterpret_cast<const float4*>(in)[j];
        ushort4 o;
        o.x = f2bf(v.x); o.y = f2bf(v.y); o.z = f2bf(v.z); o.w = f2bf(v.w);
        reinterpret_cast<ushort4*>(out)[j] = o;
    }
}

// interleave gate/up weights: W13[32g + j] = w1[16g + j]; W13[32g + 16 + j] = w3[16g + j]
__global__ __launch_bounds__(256) void cvt13_kernel(const float* __restrict__ w1,
                                                    const float* __restrict__ w3,
                                                    unsigned short* __restrict__ W13,
                                                    int n4) {
    int stride = gridDim.x * blockDim.x;
    for (int j = blockIdx.x * blockDim.x + threadIdx.x; j < n4; j += stride) {
        int flat = j << 2;
        int R = flat >> 11;          // row (DIM_H = 2048 cols)
        int col = flat & 2047;
        int orow = ((R >> 4) << 5) | (R & 15);
        float4 v1 = reinterpret_cast<const float4*>(w1)[j];
        float4 v3 = reinterpret_cast<const float4*>(w3)[j];
        ushort4 o1, o3;
        o1.x=f2bf(v1.x); o1.y=f2bf(v1.y); o1.z=f2bf(v1.z); o1.w=f2bf(v1.w);
        o3.x=f2bf(v3.x); o3.y=f2bf(v3.y); o3.z=f2bf(v3.z); o3.w=f2bf(v3.w);
        *reinterpret_cast<ushort4*>(&W13[(size_t)orow * DIM_H + col]) = o1;
        *reinterpret_cast<ushort4*>(&W13[(size_t)(orow + 16) * DIM_H + col]) = o3;
    }
}

// ---------------- mask compaction (256-row padding) ----------------
__global__ __launch_bounds__(256) void compact_kernel(const int* __restrict__ mask,
                                                      int* __restrict__ idx,
                                                      int* __restrict__ hdr) {
    __shared__ int cnt[256];
    const int t = threadIdx.x;
    const int base = t * 32;
    unsigned bits = 0;
#pragma unroll
    for (int j = 0; j < 32; ++j)
        if (mask[base + j] != 0) bits |= (1u << j);
    const int c = __popc(bits);
    cnt[t] = c;
    __syncthreads();
    for (int off = 1; off < 256; off <<= 1) {
        int v = cnt[t];
        int add = (t >= off) ? cnt[t - off] : 0;
        __syncthreads();
        cnt[t] = v + add;
        __syncthreads();
    }
    const int Mw  = cnt[255];
    const int MwP = (Mw + 255) & ~255;
    const int Mu  = TOKENS - Mw;
    const int MuP = (Mu + 255) & ~255;

    for (int j = t; j < CROWS; j += 256) idx[j] = -1;
    __syncthreads();

    int pw = cnt[t] - c;
    int pz = base - pw;
#pragma unroll
    for (int j = 0; j < 32; ++j) {
        int tok = base + j;
        if ((bits >> j) & 1) idx[pw++] = tok;
        else                 idx[MwP + pz++] = tok;
    }
    if (t == 0) {
        hdr[0] = MwP >> 8;           // w-blocks (256-row units)
        hdr[1] = (MwP + MuP) >> 8;   // total blocks
        hdr[2] = Mw;
        hdr[3] = Mu;
    }
}

// ================= 256x256 / BK=64 / 8 waves (2Mx4N), 2 phases/K-tile, unrolled x2 =================
// LDS 128KB: 2 buf x { A_k0@0, A_k1@8192, B_k0@16384, B_k1@24576 } slices of 256x32 elems (16KB).
// swizzle (16B units): phys c16' = c16 ^ ((row>>1)&3), applied on pre-swizzled global src + ds_read.

#define LDF4(D0,D1,D2,D3, SB, RB) do { \
    const unsigned short* _sl = &smem[(SB)]; \
    D0 = *reinterpret_cast<const bf16x8*>(&_sl[((RB) +  0)*32 + c16r]); \
    D1 = *reinterpret_cast<const bf16x8*>(&_sl[((RB) + 16)*32 + c16r]); \
    D2 = *reinterpret_cast<const bf16x8*>(&_sl[((RB) + 32)*32 + c16r]); \
    D3 = *reinterpret_cast<const bf16x8*>(&_sl[((RB) + 48)*32 + c16r]); \
} while(0)

#define STAGE2(UB_, S0_, S1_, KOFS_) do { \
    __builtin_amdgcn_global_load_lds((const __attribute__((address_space(1))) void*)((S0_) + (KOFS_)), \
        (__attribute__((address_space(3))) void*)&smem[(UB_) + wave*512], 16, 0, 0); \
    __builtin_amdgcn_global_load_lds((const __attribute__((address_space(1))) void*)((S1_) + (KOFS_)), \
        (__attribute__((address_space(3))) void*)&smem[(UB_) + 4096 + wave*512], 16, 0, 0); \
} while(0)

#define MFMA32() do { \
  __builtin_amdgcn_s_setprio(1); \
  acc[0][0]=MF(af0,bfr0,acc[0][0]); acc[0][1]=MF(af0,bfr1,acc[0][1]); acc[0][2]=MF(af0,bfr2,acc[0][2]); acc[0][3]=MF(af0,bfr3,acc[0][3]); \
  acc[1][0]=MF(af1,bfr0,acc[1][0]); acc[1][1]=MF(af1,bfr1,acc[1][1]); acc[1][2]=MF(af1,bfr2,acc[1][2]); acc[1][3]=MF(af1,bfr3,acc[1][3]); \
  acc[2][0]=MF(af2,bfr0,acc[2][0]); acc[2][1]=MF(af2,bfr1,acc[2][1]); acc[2][2]=MF(af2,bfr2,acc[2][2]); acc[2][3]=MF(af2,bfr3,acc[2][3]); \
  acc[3][0]=MF(af3,bfr0,acc[3][0]); acc[3][1]=MF(af3,bfr1,acc[3][1]); acc[3][2]=MF(af3,bfr2,acc[3][2]); acc[3][3]=MF(af3,bfr3,acc[3][3]); \
  acc[4][0]=MF(af4,bfr0,acc[4][0]); acc[4][1]=MF(af4,bfr1,acc[4][1]); acc[4][2]=MF(af4,bfr2,acc[4][2]); acc[4][3]=MF(af4,bfr3,acc[4][3]); \
  acc[5][0]=MF(af5,bfr0,acc[5][0]); acc[5][1]=MF(af5,bfr1,acc[5][1]); acc[5][2]=MF(af5,bfr2,acc[5][2]); acc[5][3]=MF(af5,bfr3,acc[5][3]); \
  acc[6][0]=MF(af6,bfr0,acc[6][0]); acc[6][1]=MF(af6,bfr1,acc[6][1]); acc[6][2]=MF(af6,bfr2,acc[6][2]); acc[6][3]=MF(af6,bfr3,acc[6][3]); \
  acc[7][0]=MF(af7,bfr0,acc[7][0]); acc[7][1]=MF(af7,bfr1,acc[7][1]); acc[7][2]=MF(af7,bfr2,acc[7][2]); acc[7][3]=MF(af7,bfr3,acc[7][3]); \
  __builtin_amdgcn_s_setprio(0); \
} while(0)

#define VMB() do { \
    asm volatile("s_waitcnt vmcnt(8)" ::: "memory"); \
    __builtin_amdgcn_s_barrier(); \
} while(0)

// one phase: 12 ds_read (const bases) + 1 STAGE2-pair (4 glls, const LDS dest) + 32 MFMA + vmcnt(8)+bar
#define PHASE(ABASE, BBASE, SA_UB, SB_UB, KO) do { \
    LDF4(af0,af1,af2,af3, (ABASE), rAb); \
    LDF4(af4,af5,af6,af7, (ABASE), rAb + 64); \
    LDF4(bfr0,bfr1,bfr2,bfr3, (BBASE), rBb); \
    STAGE2((SA_UB), sa0, sa1, (KO)); \
    STAGE2((SB_UB), sb0, sb1, (KO)); \
    MFMA32(); \
    VMB(); \
} while(0)

// Unrolled 2-tile K loop: all LDS bases compile-time consts; pointers bump +128/pair.
// Schedule (R7-proven): P1(t): read t.k0, stage (t+1).k1 -> nxt ; P2(t): read t.k1, stage (t+2).k0 -> cur
#define KLOOP(NT) do { \
    STAGE2(0,     sa0, sa1, 0);   STAGE2(16384, sb0, sb1, 0);   /* t0.k0 */ \
    STAGE2(8192,  sa0, sa1, 32);  STAGE2(24576, sb0, sb1, 32);  /* t0.k1 */ \
    STAGE2(32768, sa0, sa1, 64);  STAGE2(49152, sb0, sb1, 64);  /* t1.k0 */ \
    VMB(); \
    for (int s = 0; s < (NT)/2; ++s) { \
        /* tile even: cur=0, nxt=32768 */ \
        PHASE(0,             16384,         32768 + 8192,  32768 + 24576, 96);   /* rd e.k0, stg o.k1 */ \
        PHASE(8192,          24576,         0,             16384,         128);  /* rd e.k1, stg e+2.k0 */ \
        /* tile odd: cur=32768, nxt=0 */ \
        PHASE(32768,         32768 + 16384, 8192,          24576,         160);  /* rd o.k0, stg o+2.k1 */ \
        PHASE(32768 + 8192,  32768 + 24576, 32768,         32768 + 16384, 192);  /* rd o.k1, stg o+2.k0... */ \
        sa0 += 128; sa1 += 128; sb0 += 128; sb1 += 128; \
    } \
} while(0)

// ---------------- GEMM1: P = silu(x@w1^T) * (x@w3^T), gathered rows, dual-branch ----------------
__global__ __launch_bounds__(512, 2) void gemm1_kernel(
    const unsigned short* __restrict__ xb,
    const unsigned short* __restrict__ W13,
    const unsigned short* __restrict__ U13,
    const int* __restrict__ idx, const int* __restrict__ hdr,
    unsigned short* __restrict__ P)
{
    __shared__ __align__(16) unsigned short smem[65536];  // 128 KB
    const int wB  = hdr[0];
    const int rbT = hdr[1];
    const int nwg = gridDim.x;                 // 64*RB256
    const int q8  = nwg >> 3;
    const int swzb = ((int)blockIdx.x & 7) * q8 + ((int)blockIdx.x >> 3);
    const int rb = swzb % RB256;               // M-block fast within XCD chunk
    const int bx = swzb / RB256;
    if (rb >= rbT) return;
    const unsigned short* Bm = (rb < wB) ? W13 : U13;
    const int bm0 = rb << 8;
    const int bn0 = bx << 8;

    const int tid  = threadIdx.x;
    const int lane = tid & 63;
    const int wave = tid >> 6;
    const int wrM = wave >> 2;
    const int wcN = wave & 3;
    const int rAb = wrM * 128 + (lane & 15);
    const int rBb = wcN * 64 + (lane & 15);
    const int c16r = (((lane >> 4) ^ ((lane >> 1) & 3))) << 3;

    const int p0 = tid, p1 = 512 + tid;
    const int r0 = p0 >> 2, r1 = p1 >> 2;
    const int c0 = ((p0 & 3) ^ ((r0 >> 1) & 3)) << 3;
    const int c1 = ((p1 & 3) ^ ((r1 >> 1) & 3)) << 3;
    int t0 = idx[bm0 + r0]; if (t0 < 0) t0 = 0;
    int t1 = idx[bm0 + r1]; if (t1 < 0) t1 = 0;
    const unsigned short* sa0 = xb + (size_t)t0 * DIM_H + c0;
    const unsigned short* sa1 = xb + (size_t)t1 * DIM_H + c1;
    const unsigned short* sb0 = Bm + (size_t)(bn0 + r0) * DIM_H + c0;
    const unsigned short* sb1 = Bm + (size_t)(bn0 + r1) * DIM_H + c1;

    f32x4 acc[8][4] = {};
    bf16x8 af0, af1, af2, af3, af4, af5, af6, af7, bfr0, bfr1, bfr2, bfr3;

    KLOOP(32);   // K = 2048

    // epilogue: n-frag pairs (2q, 2q+1) = (h1, h3) for the same 16 P-cols
    const int crow = (lane >> 4) << 2;
    const int ccol = lane & 15;
    unsigned short* Pw = P + (size_t)(bm0 + wrM * 128) * DIM_I
                           + (size_t)bx * 128 + wcN * 32 + ccol;
#pragma unroll
    for (int m = 0; m < 8; ++m) {
#pragma unroll
        for (int q = 0; q < 2; ++q) {
            f32x4 h1 = acc[m][2 * q];
            f32x4 h3 = acc[m][2 * q + 1];
#pragma unroll
            for (int r = 0; r < 4; ++r) {
                float a = h1[r];
                float p = a * (1.0f / (1.0f + __expf(-a))) * h3[r];
                Pw[(size_t)(m * 16 + crow + r) * DIM_I + q * 16] = f2bf(p);
            }
        }
    }
}

// ---------------- GEMM2: out[idx[c]] = P[c] @ w2^T  (256x256 clone of gemm1 loop) ----------------
__global__ __launch_bounds__(512, 2) void gemm2_kernel(
    const unsigned short* __restrict__ P,
    const unsigned short* __restrict__ w2b, const unsigned short* __restrict__ u2b,
    const int* __restrict__ idx, const int* __restrict__ hdr,
    float* __restrict__ out)
{
    __shared__ __align__(16) unsigned short smem[65536];  // 128 KB
    const int wB  = hdr[0];
    const int rbT = hdr[1];
    const int nwg = gridDim.x;                 // 8*RB256 = 272 -> 34 blocks per XCD chunk
    const int q8  = nwg >> 3;                  // 34
    const int swzb = ((int)blockIdx.x & 7) * q8 + ((int)blockIdx.x >> 3);
    const int rb = swzb % RB256;               // M fast; each XCD owns exactly one bx panel (4MB, L2-resident)
    const int bx = swzb / RB256;
    if (rb >= rbT) return;
    const unsigned short* Bm = (rb < wB) ? w2b : u2b;
    const int bm0 = rb << 8;
    const int bn0 = bx << 8;

    const int tid  = threadIdx.x;
    const int lane = tid & 63;
    const int wave = tid >> 6;
    const int wrM = wave >> 2;
    const int wcN = wave & 3;
    const int rAb = wrM * 128 + (lane & 15);
    const int rBb = wcN * 64 + (lane & 15);
    const int c16r = (((lane >> 4) ^ ((lane >> 1) & 3))) << 3;

    const int p0 = tid, p1 = 512 + tid;
    const int r0 = p0 >> 2, r1 = p1 >> 2;
    const int c0 = ((p0 & 3) ^ ((r0 >> 1) & 3)) << 3;
    const int c1 = ((p1 & 3) ^ ((r1 >> 1) & 3)) << 3;
    const unsigned short* sa0 = P  + (size_t)(bm0 + r0) * DIM_I + c0;
    const unsigned short* sa1 = P  + (size_t)(bm0 + r1) * DIM_I + c1;
    const unsigned short* sb0 = Bm + (size_t)(bn0 + r0) * DIM_I + c0;
    const unsigned short* sb1 = Bm + (size_t)(bn0 + r1) * DIM_I + c1;

    f32x4 acc[8][4] = {};
    bf16x8 af0, af1, af2, af3, af4, af5, af6, af7, bfr0, bfr1, bfr2, bfr3;

    KLOOP(128);  // K = 8192

    const int crow = (lane >> 4) << 2;
    const int ccol = lane & 15;
#pragma unroll
    for (int m = 0; m < 8; ++m) {
#pragma unroll
        for (int r = 0; r < 4; ++r) {
            int rowc = bm0 + wrM * 128 + m * 16 + crow + r;
            int g = idx[rowc];
            if (g >= 0) {
                float* op = out + (size_t)g * DIM_H + bn0 + wcN * 64 + ccol;
#pragma unroll
                for (int n = 0; n < 4; ++n) op[n * 16] = acc[m][n][r];
            }
        }
    }
}

extern "C" void kernel_launch(void* const* d_in, const int* in_sizes, int n_in,
                              void* d_out, int out_size, void* d_ws, size_t ws_size,
                              hipStream_t stream) {
    const float* x    = (const float*)d_in[0];
    const int*   mask = (const int*)d_in[1];
    const float* w1 = (const float*)d_in[2];
    const float* w2 = (const float*)d_in[3];
    const float* w3 = (const float*)d_in[4];
    const float* u1 = (const float*)d_in[5];
    const float* u2 = (const float*)d_in[6];
    const float* u3 = (const float*)d_in[7];
    float* out = (float*)d_out;

    const size_t XN   = (size_t)TOKENS * DIM_H;      // 16.78M
    const size_t WN   = (size_t)DIM_I * DIM_H;       // 16.78M
    const size_t PN   = (size_t)CROWS * DIM_I;       // 71.3M
    const size_t W13N = 2 * WN;                      // 33.55M

    unsigned short* ws  = (unsigned short*)d_ws;
    unsigned short* xb  = ws;                        // XN
    unsigned short* Pb  = xb + XN;                   // PN
    unsigned short* W13 = Pb + PN;                   // W13N
    unsigned short* U13 = W13 + W13N;                // W13N
    int* idx = (int*)(U13 + W13N);                   // CROWS ints
    int* hdr = idx + CROWS;                          // 8 ints
    unsigned short* w2b = W13;                       // reuse after gemm1
    unsigned short* u2b = U13;

    const int cvtBlocks = 2048;
    const int n4 = (int)(WN / 4);

    cvt_kernel  <<<cvtBlocks, 256, 0, stream>>>(x, xb, (int)(XN / 4));
    cvt13_kernel<<<cvtBlocks, 256, 0, stream>>>(w1, w3, W13, n4);
    cvt13_kernel<<<cvtBlocks, 256, 0, stream>>>(u1, u3, U13, n4);
    compact_kernel<<<1, 256, 0, stream>>>(mask, idx, hdr);

    gemm1_kernel<<<64 * RB256, 512, 0, stream>>>(xb, W13, U13, idx, hdr, Pb);

    cvt_kernel<<<cvtBlocks, 256, 0, stream>>>(w2, w2b, n4);
    cvt_kernel<<<cvtBlocks, 256, 0, stream>>>(u2, u2b, n4);

    gemm2_kernel<<<8 * RB256, 512, 0, stream>>>(Pb, w2b, u2b, idx, hdr, out);
}

// Round 10
// 1057.706 us; speedup vs baseline: 1.0625x; 1.0388x over previous
//
#include <hip/hip_runtime.h>
#include <hip/hip_bf16.h>
#include <stdint.h>

#define DIM_H 2048
#define DIM_I 8192
#define TOKENS 8192
#define RB256 34            // max 256-row compacted blocks (32 + 2 pad)
#define CROWS (RB256*256)   // 8704

typedef __attribute__((ext_vector_type(8))) short bf16x8;
typedef __attribute__((ext_vector_type(4))) float f32x4;

#define MF(a,b,c) __builtin_amdgcn_mfma_f32_16x16x32_bf16((a),(b),(c),0,0,0)

__device__ __forceinline__ unsigned short f2bf(float f) {
    union { float f; unsigned u; } v; v.f = f;
    return (unsigned short)((v.u + 0x7FFF + ((v.u >> 16) & 1)) >> 16);
}

// ---------------- fp32 -> bf16 conversion ----------------
__global__ __launch_bounds__(256) void cvt_kernel(const float* __restrict__ in,
                                                  unsigned short* __restrict__ out,
                                                  int n4) {
    int stride = gridDim.x * blockDim.x;
    for (int j = blockIdx.x * blockDim.x + threadIdx.x; j < n4; j += stride) {
        float4 v = reinterpret_cast<const float4*>(in)[j];
        ushort4 o;
        o.x = f2bf(v.x); o.y = f2bf(v.y); o.z = f2bf(v.z); o.w = f2bf(v.w);
        reinterpret_cast<ushort4*>(out)[j] = o;
    }
}

// interleave gate/up weights: W13[32g + j] = w1[16g + j]; W13[32g + 16 + j] = w3[16g + j]
__global__ __launch_bounds__(256) void cvt13_kernel(const float* __restrict__ w1,
                                                    const float* __restrict__ w3,
                                                    unsigned short* __restrict__ W13,
                                                    int n4) {
    int stride = gridDim.x * blockDim.x;
    for (int j = blockIdx.x * blockDim.x + threadIdx.x; j < n4; j += stride) {
        int flat = j << 2;
        int R = flat >> 11;          // row (DIM_H = 2048 cols)
        int col = flat & 2047;
        int orow = ((R >> 4) << 5) | (R & 15);
        float4 v1 = reinterpret_cast<const float4*>(w1)[j];
        float4 v3 = reinterpret_cast<const float4*>(w3)[j];
        ushort4 o1, o3;
        o1.x=f2bf(v1.x); o1.y=f2bf(v1.y); o1.z=f2bf(v1.z); o1.w=f2bf(v1.w);
        o3.x=f2bf(v3.x); o3.y=f2bf(v3.y); o3.z=f2bf(v3.z); o3.w=f2bf(v3.w);
        *reinterpret_cast<ushort4*>(&W13[(size_t)orow * DIM_H + col]) = o1;
        *reinterpret_cast<ushort4*>(&W13[(size_t)(orow + 16) * DIM_H + col]) = o3;
    }
}

// ---------------- mask compaction (256-row padding) ----------------
__global__ __launch_bounds__(256) void compact_kernel(const int* __restrict__ mask,
                                                      int* __restrict__ idx,
                                                      int* __restrict__ hdr) {
    __shared__ int cnt[256];
    const int t = threadIdx.x;
    const int base = t * 32;
    unsigned bits = 0;
#pragma unroll
    for (int j = 0; j < 32; ++j)
        if (mask[base + j] != 0) bits |= (1u << j);
    const int c = __popc(bits);
    cnt[t] = c;
    __syncthreads();
    for (int off = 1; off < 256; off <<= 1) {
        int v = cnt[t];
        int add = (t >= off) ? cnt[t - off] : 0;
        __syncthreads();
        cnt[t] = v + add;
        __syncthreads();
    }
    const int Mw  = cnt[255];
    const int MwP = (Mw + 255) & ~255;
    const int Mu  = TOKENS - Mw;
    const int MuP = (Mu + 255) & ~255;

    for (int j = t; j < CROWS; j += 256) idx[j] = -1;
    __syncthreads();

    int pw = cnt[t] - c;
    int pz = base - pw;
#pragma unroll
    for (int j = 0; j < 32; ++j) {
        int tok = base + j;
        if ((bits >> j) & 1) idx[pw++] = tok;
        else                 idx[MwP + pz++] = tok;
    }
    if (t == 0) {
        hdr[0] = MwP >> 8;           // w-blocks (256-row units)
        hdr[1] = (MwP + MuP) >> 8;   // total blocks
        hdr[2] = Mw;
        hdr[3] = Mu;
    }
}

// ================= shared GEMM machinery =================
// slice = R rows x 32 cols bf16 (64B rows); swizzle (16B units): phys c' = c16 ^ ((row>>1)&3)
// applied identically on pre-swizzled global src + ds_read addr (both-sides involution).

#define LDF4(D0,D1,D2,D3, SB, RB) do { \
    const unsigned short* _sl = &smem[(SB)]; \
    D0 = *reinterpret_cast<const bf16x8*>(&_sl[((RB) +  0)*32 + c16r]); \
    D1 = *reinterpret_cast<const bf16x8*>(&_sl[((RB) + 16)*32 + c16r]); \
    D2 = *reinterpret_cast<const bf16x8*>(&_sl[((RB) + 32)*32 + c16r]); \
    D3 = *reinterpret_cast<const bf16x8*>(&_sl[((RB) + 48)*32 + c16r]); \
} while(0)

#define STAGE2(UB_, S0_, S1_, KOFS_) do { \
    __builtin_amdgcn_global_load_lds((const __attribute__((address_space(1))) void*)((S0_) + (KOFS_)), \
        (__attribute__((address_space(3))) void*)&smem[(UB_) + wave*512], 16, 0, 0); \
    __builtin_amdgcn_global_load_lds((const __attribute__((address_space(1))) void*)((S1_) + (KOFS_)), \
        (__attribute__((address_space(3))) void*)&smem[(UB_) + 4096 + wave*512], 16, 0, 0); \
} while(0)

#define STAGE1(UB_, S0_, KOFS_) \
    __builtin_amdgcn_global_load_lds((const __attribute__((address_space(1))) void*)((S0_) + (KOFS_)), \
        (__attribute__((address_space(3))) void*)&smem[(UB_) + wave*512], 16, 0, 0)

// ---------------- GEMM1: 256x256 / BK=64 / 8 waves (2Mx4N) / X-Y frag pipelined ----------------
// LDS 128KB: 2 buf x { A_k0@0, A_k1@8192, B_k0@16384, B_k1@24576 }, slices 256x32 (8192 elems).
// Phase p reads NEXT slice's fragments before MFMA of current slice -> counted lgkm overlap.
#define MFMA32_S(A0,A1,A2,A3,A4,A5,A6,A7,B0,B1,B2,B3) do { \
  __builtin_amdgcn_s_setprio(1); \
  acc[0][0]=MF(A0,B0,acc[0][0]); acc[0][1]=MF(A0,B1,acc[0][1]); acc[0][2]=MF(A0,B2,acc[0][2]); acc[0][3]=MF(A0,B3,acc[0][3]); \
  acc[1][0]=MF(A1,B0,acc[1][0]); acc[1][1]=MF(A1,B1,acc[1][1]); acc[1][2]=MF(A1,B2,acc[1][2]); acc[1][3]=MF(A1,B3,acc[1][3]); \
  acc[2][0]=MF(A2,B0,acc[2][0]); acc[2][1]=MF(A2,B1,acc[2][1]); acc[2][2]=MF(A2,B2,acc[2][2]); acc[2][3]=MF(A2,B3,acc[2][3]); \
  acc[3][0]=MF(A3,B0,acc[3][0]); acc[3][1]=MF(A3,B1,acc[3][1]); acc[3][2]=MF(A3,B2,acc[3][2]); acc[3][3]=MF(A3,B3,acc[3][3]); \
  acc[4][0]=MF(A4,B0,acc[4][0]); acc[4][1]=MF(A4,B1,acc[4][1]); acc[4][2]=MF(A4,B2,acc[4][2]); acc[4][3]=MF(A4,B3,acc[4][3]); \
  acc[5][0]=MF(A5,B0,acc[5][0]); acc[5][1]=MF(A5,B1,acc[5][1]); acc[5][2]=MF(A5,B2,acc[5][2]); acc[5][3]=MF(A5,B3,acc[5][3]); \
  acc[6][0]=MF(A6,B0,acc[6][0]); acc[6][1]=MF(A6,B1,acc[6][1]); acc[6][2]=MF(A6,B2,acc[6][2]); acc[6][3]=MF(A6,B3,acc[6][3]); \
  acc[7][0]=MF(A7,B0,acc[7][0]); acc[7][1]=MF(A7,B1,acc[7][1]); acc[7][2]=MF(A7,B2,acc[7][2]); acc[7][3]=MF(A7,B3,acc[7][3]); \
  __builtin_amdgcn_s_setprio(0); \
} while(0)

__global__ __launch_bounds__(512, 2) void gemm1_kernel(
    const unsigned short* __restrict__ xb,
    const unsigned short* __restrict__ W13,
    const unsigned short* __restrict__ U13,
    const int* __restrict__ idx, const int* __restrict__ hdr,
    unsigned short* __restrict__ P)
{
    __shared__ __align__(16) unsigned short smem[65536];  // 128 KB
    const int wB  = hdr[0];
    const int rbT = hdr[1];
    const int nwg = gridDim.x;                 // 64*RB256
    const int q8  = nwg >> 3;
    const int swzb = ((int)blockIdx.x & 7) * q8 + ((int)blockIdx.x >> 3);
    const int rb = swzb % RB256;               // M-block fast within XCD chunk
    const int bx = swzb / RB256;
    if (rb >= rbT) return;
    const unsigned short* Bm = (rb < wB) ? W13 : U13;
    const int bm0 = rb << 8;
    const int bn0 = bx << 8;

    const int tid  = threadIdx.x;
    const int lane = tid & 63;
    const int wave = tid >> 6;
    const int wrM = wave >> 2;
    const int wcN = wave & 3;
    const int rAb = wrM * 128 + (lane & 15);
    const int rBb = wcN * 64 + (lane & 15);
    const int c16r = (((lane >> 4) ^ ((lane >> 1) & 3))) << 3;

    const int p0 = tid, p1 = 512 + tid;
    const int r0 = p0 >> 2, r1 = p1 >> 2;
    const int c0 = ((p0 & 3) ^ ((r0 >> 1) & 3)) << 3;
    const int c1 = ((p1 & 3) ^ ((r1 >> 1) & 3)) << 3;
    int t0 = idx[bm0 + r0]; if (t0 < 0) t0 = 0;
    int t1 = idx[bm0 + r1]; if (t1 < 0) t1 = 0;
    const unsigned short* sa0 = xb + (size_t)t0 * DIM_H + c0;
    const unsigned short* sa1 = xb + (size_t)t1 * DIM_H + c1;
    const unsigned short* sb0 = Bm + (size_t)(bn0 + r0) * DIM_H + c0;
    const unsigned short* sb1 = Bm + (size_t)(bn0 + r1) * DIM_H + c1;

    f32x4 acc[8][4] = {};
    bf16x8 xa0,xa1,xa2,xa3,xa4,xa5,xa6,xa7, xb0,xb1,xb2,xb3;
    bf16x8 ya0,ya1,ya2,ya3,ya4,ya5,ya6,ya7, yb0,yb1,yb2,yb3;

    // prologue: t0 {k0,k1}, t1 {k0}
    STAGE2(0,     sa0, sa1, 0);   STAGE2(16384, sb0, sb1, 0);   // t0.k0
    STAGE2(8192,  sa0, sa1, 32);  STAGE2(24576, sb0, sb1, 32);  // t0.k1
    STAGE2(32768, sa0, sa1, 64);  STAGE2(49152, sb0, sb1, 64);  // t1.k0
    asm volatile("s_waitcnt vmcnt(4)" ::: "memory");             // t0.k0 + t0.k1 landed
    __builtin_amdgcn_s_barrier();
    // X <- t0.k0
    LDF4(xa0,xa1,xa2,xa3, 0, rAb);
    LDF4(xa4,xa5,xa6,xa7, 0, rAb + 64);
    LDF4(xb0,xb1,xb2,xb3, 16384, rBb);
    int ko = 96;
    for (int t = 0; t < 32; ++t) {
        const int cur = (t & 1) << 15;
        const int nxt = cur ^ 32768;
        // P1: Y <- t.k1 ; stage (t+1).k1 -> nxt ; MFMA(X = t.k0)
        LDF4(ya0,ya1,ya2,ya3, cur + 8192,  rAb);
        LDF4(ya4,ya5,ya6,ya7, cur + 8192,  rAb + 64);
        LDF4(yb0,yb1,yb2,yb3, cur + 24576, rBb);
        STAGE2(nxt + 8192,  sa0, sa1, ko);
        STAGE2(nxt + 24576, sb0, sb1, ko);
        MFMA32_S(xa0,xa1,xa2,xa3,xa4,xa5,xa6,xa7, xb0,xb1,xb2,xb3);
        asm volatile("s_waitcnt vmcnt(4)" ::: "memory");   // (t+1).k0 (staged P2(t-1)) landed
        __builtin_amdgcn_s_barrier();
        // P2: X <- (t+1).k0 ; stage (t+2).k0 -> cur ; MFMA(Y = t.k1)
        LDF4(xa0,xa1,xa2,xa3, nxt,         rAb);
        LDF4(xa4,xa5,xa6,xa7, nxt,         rAb + 64);
        LDF4(xb0,xb1,xb2,xb3, nxt + 16384, rBb);
        STAGE2(cur,         sa0, sa1, ko + 32);
        STAGE2(cur + 16384, sb0, sb1, ko + 32);
        ko += 64;
        MFMA32_S(ya0,ya1,ya2,ya3,ya4,ya5,ya6,ya7, yb0,yb1,yb2,yb3);
        asm volatile("s_waitcnt vmcnt(4)" ::: "memory");   // (t+1).k1 (staged P1(t)) landed
        __builtin_amdgcn_s_barrier();
    }

    // epilogue: n-frag pairs (2q, 2q+1) = (h1, h3) for the same 16 P-cols
    const int crow = (lane >> 4) << 2;
    const int ccol = lane & 15;
    unsigned short* Pw = P + (size_t)(bm0 + wrM * 128) * DIM_I
                           + (size_t)bx * 128 + wcN * 32 + ccol;
#pragma unroll
    for (int m = 0; m < 8; ++m) {
#pragma unroll
        for (int q = 0; q < 2; ++q) {
            f32x4 h1 = acc[m][2 * q];
            f32x4 h3 = acc[m][2 * q + 1];
#pragma unroll
            for (int r = 0; r < 4; ++r) {
                float a = h1[r];
                float p = a * (1.0f / (1.0f + __expf(-a))) * h3[r];
                Pw[(size_t)(m * 16 + crow + r) * DIM_I + q * 16] = f2bf(p);
            }
        }
    }
}

// ---------------- GEMM2: 128x256 / BK=64 / 8 waves (2Mx4N) / triple-buffer, frag-pipelined ----
// LDS 144KB: 3 buf x { A[128x32]k0, A k1, B[256x32]k0, B k1 } = 48KB (24576 elems) each
#define MFMA16Q(AF0,AF1,AF2,AF3, B0,B1,B2,B3) do { \
  __builtin_amdgcn_s_setprio(1); \
  acc[0][0]=MF(AF0,B0,acc[0][0]); acc[0][1]=MF(AF0,B1,acc[0][1]); acc[0][2]=MF(AF0,B2,acc[0][2]); acc[0][3]=MF(AF0,B3,acc[0][3]); \
  acc[1][0]=MF(AF1,B0,acc[1][0]); acc[1][1]=MF(AF1,B1,acc[1][1]); acc[1][2]=MF(AF1,B2,acc[1][2]); acc[1][3]=MF(AF1,B3,acc[1][3]); \
  acc[2][0]=MF(AF2,B0,acc[2][0]); acc[2][1]=MF(AF2,B1,acc[2][1]); acc[2][2]=MF(AF2,B2,acc[2][2]); acc[2][3]=MF(AF2,B3,acc[2][3]); \
  acc[3][0]=MF(AF3,B0,acc[3][0]); acc[3][1]=MF(AF3,B1,acc[3][1]); acc[3][2]=MF(AF3,B2,acc[3][2]); acc[3][3]=MF(AF3,B3,acc[3][3]); \
  __builtin_amdgcn_s_setprio(0); \
} while(0)

__global__ __launch_bounds__(512, 2) void gemm2_kernel(
    const unsigned short* __restrict__ P,
    const unsigned short* __restrict__ w2b, const unsigned short* __restrict__ u2b,
    const int* __restrict__ idx, const int* __restrict__ hdr,
    float* __restrict__ out)
{
    __shared__ __align__(16) unsigned short smem[73728];  // 144 KB
    const int wB2  = hdr[0] * 2;               // 128-row units
    const int rbT2 = hdr[1] * 2;
    const int nwg = gridDim.x;                 // 8 * 68 = 544
    const int q8  = nwg >> 3;                  // 68
    const int swz = ((int)blockIdx.x & 7) * q8 + ((int)blockIdx.x >> 3);
    const int rb = swz % 68;                   // M-block fast -> each XCD pins one bx panel
    const int bx = swz / 68;
    if (rb >= rbT2) return;
    const unsigned short* Bm = (rb < wB2) ? w2b : u2b;
    const int bm0 = rb << 7;                   // *128
    const int bn0 = bx << 8;                   // *256

    const int tid  = threadIdx.x;
    const int lane = tid & 63;
    const int wave = tid >> 6;
    const int wrM = wave >> 2;                 // 0..1
    const int wcN = wave & 3;                  // 0..3
    const int rAb = wrM * 64 + (lane & 15);
    const int rBb = wcN * 64 + (lane & 15);
    const int c16r = (((lane >> 4) ^ ((lane >> 1) & 3))) << 3;

    const int r0 = tid >> 2, r1 = 128 + r0;
    const int c0 = ((tid & 3) ^ ((r0 >> 1) & 3)) << 3;
    const int c1 = ((tid & 3) ^ ((r1 >> 1) & 3)) << 3;
    const unsigned short* sa0 = P  + (size_t)(bm0 + r0) * DIM_I + c0;   // A rows 0..127
    const unsigned short* sb0 = Bm + (size_t)(bn0 + r0) * DIM_I + c0;
    const unsigned short* sb1 = Bm + (size_t)(bn0 + r1) * DIM_I + c1;

    f32x4 acc[4][4] = {};
    bf16x8 af0, af1, af2, af3, af4, af5, af6, af7;
    bf16x8 bfr0, bfr1, bfr2, bfr3, bfr4, bfr5, bfr6, bfr7;

    // prologue: t0 -> buf0, t1 -> buf1
    STAGE1(0,     sa0, 0);
    STAGE1(4096,  sa0, 32);
    STAGE2(8192,  sb0, sb1, 0);
    STAGE2(16384, sb0, sb1, 32);
    STAGE1(24576,         sa0, 64);
    STAGE1(24576 + 4096,  sa0, 96);
    STAGE2(24576 + 8192,  sb0, sb1, 64);
    STAGE2(24576 + 16384, sb0, sb1, 96);
    asm volatile("s_waitcnt vmcnt(6)" ::: "memory");   // t0 ready
    __builtin_amdgcn_s_barrier();
    int ko = 128, cb = 0;
    for (int t = 0; t < 128; ++t) {
        const int base = cb * 24576;
        int nb = base + 49152; if (nb >= 73728) nb -= 73728;   // (cb+2)%3
        // reads (16 b128)
        LDF4(af0,af1,af2,af3,     base,          rAb);
        LDF4(af4,af5,af6,af7,     base + 4096,   rAb);
        LDF4(bfr0,bfr1,bfr2,bfr3, base + 8192,   rBb);
        LDF4(bfr4,bfr5,bfr6,bfr7, base + 16384,  rBb);
        // stage t+2 -> nb
        STAGE1(nb,         sa0, ko);
        STAGE1(nb + 4096,  sa0, ko + 32);
        STAGE2(nb + 8192,  sb0, sb1, ko);
        STAGE2(nb + 16384, sb0, sb1, ko + 32);
        ko += 64;
        MFMA16Q(af0,af1,af2,af3, bfr0,bfr1,bfr2,bfr3);   // k0
        MFMA16Q(af4,af5,af6,af7, bfr4,bfr5,bfr6,bfr7);   // k1
        asm volatile("s_waitcnt vmcnt(6)" ::: "memory"); // t+1's loads landed (2-phase cover)
        __builtin_amdgcn_s_barrier();
        cb = (cb == 2) ? 0 : cb + 1;
    }

    const int crow = (lane >> 4) << 2;
    const int ccol = lane & 15;
#pragma unroll
    for (int m = 0; m < 4; ++m) {
#pragma unroll
        for (int r = 0; r < 4; ++r) {
            int rowc = bm0 + wrM * 64 + m * 16 + crow + r;
            int g = idx[rowc];
            if (g >= 0) {
                float* op = out + (size_t)g * DIM_H + bn0 + wcN * 64 + ccol;
#pragma unroll
                for (int n = 0; n < 4; ++n) op[n * 16] = acc[m][n][r];
            }
        }
    }
}

extern "C" void kernel_launch(void* const* d_in, const int* in_sizes, int n_in,
                              void* d_out, int out_size, void* d_ws, size_t ws_size,
                              hipStream_t stream) {
    const float* x    = (const float*)d_in[0];
    const int*   mask = (const int*)d_in[1];
    const float* w1 = (const float*)d_in[2];
    const float* w2 = (const float*)d_in[3];
    const float* w3 = (const float*)d_in[4];
    const float* u1 = (const float*)d_in[5];
    const float* u2 = (const float*)d_in[6];
    const float* u3 = (const float*)d_in[7];
    float* out = (float*)d_out;

    const size_t XN   = (size_t)TOKENS * DIM_H;      // 16.78M
    const size_t WN   = (size_t)DIM_I * DIM_H;       // 16.78M
    const size_t PN   = (size_t)CROWS * DIM_I;       // 71.3M
    const size_t W13N = 2 * WN;                      // 33.55M

    unsigned short* ws  = (unsigned short*)d_ws;
    unsigned short* xb  = ws;                        // XN
    unsigned short* Pb  = xb + XN;                   // PN
    unsigned short* W13 = Pb + PN;                   // W13N
    unsigned short* U13 = W13 + W13N;                // W13N
    int* idx = (int*)(U13 + W13N);                   // CROWS ints
    int* hdr = idx + CROWS;                          // 8 ints
    unsigned short* w2b = W13;                       // reuse after gemm1
    unsigned short* u2b = U13;

    const int cvtBlocks = 2048;
    const int n4 = (int)(WN / 4);

    cvt_kernel  <<<cvtBlocks, 256, 0, stream>>>(x, xb, (int)(XN / 4));
    cvt13_kernel<<<cvtBlocks, 256, 0, stream>>>(w1, w3, W13, n4);
    cvt13_kernel<<<cvtBlocks, 256, 0, stream>>>(u1, u3, U13, n4);
    compact_kernel<<<1, 256, 0, stream>>>(mask, idx, hdr);

    gemm1_kernel<<<64 * RB256, 512, 0, stream>>>(xb, W13, U13, idx, hdr, Pb);

    cvt_kernel<<<cvtBlocks, 256, 0, stream>>>(w2, w2b, n4);
    cvt_kernel<<<cvtBlocks, 256, 0, stream>>>(u2, u2b, n4);

    gemm2_kernel<<<8 * 68, 512, 0, stream>>>(Pb, w2b, u2b, idx, hdr, out);
}